// Round 1
// baseline (127.813 us; speedup 1.0000x reference)
//
#include <hip/hip_runtime.h>
#include <stdint.h>

#define BATCH 256
#define IDIM  8192
#define ODIM  8192
#define MS    64
#define IC    128
#define OC    128
#define NB    1024

// GEMM geometry: 256x256 tile, BK=64, 8 waves (2M x 4N), wave tile 128x64
#define BM 256
#define BN 256
#define BK 64
#define KSPLIT 8
#define KT (IC / KSPLIT)           // 16 K-tiles per workgroup

// dynamic LDS layout (ushort offsets): A dbuf 2 x 16384, B dbuf 2 x 16384 = 128 KB
#define ABUF(s) ((s) * 16384)
#define BBUF(s) (32768 + (s) * 16384)

typedef __bf16 bf16x8 __attribute__((ext_vector_type(8)));
typedef float  floatx4 __attribute__((ext_vector_type(4)));

// s_waitcnt imm: vmcnt[3:0]|[15:14], expcnt/lgkmcnt = don't-care
#define WAITCNT_VM(n) ((((n) & 15) | (((n) >> 4) << 14)) | 0x70 | 0xF00)

__device__ __forceinline__ void async_load16(unsigned short* lds_p, const unsigned short* g_p) {
    __builtin_amdgcn_global_load_lds(
        (const __attribute__((address_space(1))) unsigned int*)g_p,
        (__attribute__((address_space(3))) unsigned int*)lds_p,
        16, 0, 0);
}

__device__ __forceinline__ unsigned short f32_to_bf16(float f) {
    unsigned int u = __float_as_uint(f);
    u += 0x7FFFu + ((u >> 16) & 1u);
    return (unsigned short)(u >> 16);
}

// ---- kernel 1: blocks -> bf16 [b][c][r] | x -> bf16 row-major | parts -> pT[ob][ib] ----
#define XCONV_BLKS 1024
#define PT_BLKS 64
__global__ void k_convert(const float* __restrict__ x, const float* __restrict__ blocks,
                          const int* __restrict__ parts,
                          unsigned short* __restrict__ xb, unsigned short* __restrict__ bt,
                          int* __restrict__ pT) {
    __shared__ float tile[MS][MS + 1];
    int b = blockIdx.x;
    if (b < NB) {
        const float4* src4 = (const float4*)(blocks + (size_t)b * MS * MS);
        unsigned short* dst = bt + (size_t)b * MS * MS;
        #pragma unroll
        for (int i = 0; i < 4; ++i) {
            int slot = i * 256 + threadIdx.x;
            int r = slot >> 4, c4 = (slot & 15) * 4;
            float4 v = src4[slot];
            tile[r][c4 + 0] = v.x; tile[r][c4 + 1] = v.y;
            tile[r][c4 + 2] = v.z; tile[r][c4 + 3] = v.w;
        }
        __syncthreads();
        #pragma unroll
        for (int i = 0; i < 2; ++i) {
            int slot = i * 256 + threadIdx.x;
            int c = slot >> 3, o = slot & 7;
            union { unsigned short s[8]; uint4 v; } u;
            #pragma unroll
            for (int j = 0; j < 8; ++j) u.s[j] = f32_to_bf16(tile[o * 8 + j][c]);
            *(uint4*)(dst + c * MS + o * 8) = u.v;        // bt[b][c][r]
        }
    } else if (b < NB + XCONV_BLKS) {
        int t = (b - NB) * 256 + threadIdx.x;
        const float4* x4 = (const float4*)x;
        float4 a = x4[2 * t], bb = x4[2 * t + 1];
        union { unsigned short s[8]; uint4 v; } u;
        u.s[0] = f32_to_bf16(a.x);  u.s[1] = f32_to_bf16(a.y);
        u.s[2] = f32_to_bf16(a.z);  u.s[3] = f32_to_bf16(a.w);
        u.s[4] = f32_to_bf16(bb.x); u.s[5] = f32_to_bf16(bb.y);
        u.s[6] = f32_to_bf16(bb.z); u.s[7] = f32_to_bf16(bb.w);
        ((uint4*)xb)[t] = u.v;
    } else {
        int t = (b - NB - XCONV_BLKS) * 256 + threadIdx.x;   // 16384
        int oc = t >> 7, ic = t & 127;
        pT[t] = parts[ic * OC + oc];                          // pT[ob][ib]
    }
}

// ---- kernel 2: GEMM 256x256, 8 waves, wave tile 128x64, A/B dbuf, 4-phase
//      schedule per K-tile: {ds_read subtile || stage-next -> barrier ->
//      setprio(1) 16xMFMA setprio(0) -> barrier} x4. Staging for tile t+1 is
//      issued in phases 0-1 of tile t and drained by one vmcnt(0) right before
//      the tile-boundary barrier (issue-early / drain-late: expected ~0 stall).
//      LDS XOR swizzle (verified 0 conflicts): LDS[r][oct] = global[r][oct ^ (r&7)]
extern __shared__ unsigned short smem[];   // 128 KB dynamic

__global__ __launch_bounds__(512, 2)
void k_mosaic_gemm(const unsigned short* __restrict__ xb,
                   const unsigned short* __restrict__ bt,
                   const int* __restrict__ pT,
                   float* __restrict__ partial) {
    const int tid  = threadIdx.x;
    const int lane = tid & 63;
    const int wave = tid >> 6;
    const int wrow = wave >> 2;      // 0..1 : 128-row band
    const int wcol = wave & 3;       // 0..3 : 64-col band
    const int ks = blockIdx.x;       // 0..7  (linear%8 -> one K-split per XCD)
    const int nt = blockIdx.y;       // 0..31

    const int ob0 = nt * 4;          // 4 output-blocks per 256-col tile
    const int kb0 = ks * KT;         // global K-tile base (0..127 step 16)

    const int row  = lane & 15;
    const int quad = lane >> 4;

    // all 4 ob x 16 ib part indices for this WG, one per lane
    int pv = pT[(ob0 + quad) * IC + kb0 + row];

    // ds_read bases: frag addr = base[kk] + mh*4096 + mi*1024 (A) / ni*1024 (B),
    // immediates folded into ds_read offset. swz: oct ^ (r&7), r&7 == row&7.
    const int swz0 = ((quad)     ^ (row & 7)) << 3;
    const int swz1 = ((quad + 4) ^ (row & 7)) << 3;
    const int a_b0 = (wrow * 128 + row) * MS + swz0;
    const int a_b1 = (wrow * 128 + row) * MS + swz1;
    const int b_b0 = (wcol * 64 + row) * MS + swz0;
    const int b_b1 = (wcol * 64 + row) * MS + swz1;

    floatx4 acc[8][4];
    #pragma unroll
    for (int mi = 0; mi < 8; ++mi)
        #pragma unroll
        for (int ni = 0; ni < 4; ++ni)
            acc[mi][ni] = (floatx4){0.f, 0.f, 0.f, 0.f};

    bf16x8 af[4], bfr[4];

    // 4 global_load_lds per thread per A-stage / per B-stage (32 KB each)
#define STAGE_A(dstS, kb) do {                                                \
    _Pragma("unroll")                                                         \
    for (int j = 0; j < 4; ++j) {                                             \
        int slot = j * 512 + tid;              /* 2048: 256 rows x 8 octets */ \
        int m = slot >> 3;                                                    \
        int oct = (slot & 7) ^ (m & 7);                                       \
        async_load16(smem + ABUF(dstS) + slot * 8,                            \
                     xb + (size_t)m * IDIM + (kb) * MS + oct * 8);            \
    } } while (0)

    // block index b == j for slot = j*512+tid (n = slot>>3, b = n>>6)
#define STAGE_B(dstS, t) do {                                                 \
    _Pragma("unroll")                                                         \
    for (int j = 0; j < 4; ++j) {                                             \
        int q = __shfl(pv, j * 16 + (t));                                     \
        int slot = j * 512 + tid;                                             \
        int n = slot >> 3;                                                    \
        int oct = (slot & 7) ^ (n & 7);                                       \
        async_load16(smem + BBUF(dstS) + slot * 8,                            \
                     bt + (size_t)q * (MS * MS) + (n & 63) * MS + oct * 8);   \
    } } while (0)

#define BARRIER_PIN() do {                                                    \
    __builtin_amdgcn_sched_barrier(0);                                        \
    __builtin_amdgcn_s_barrier();                                             \
    __builtin_amdgcn_sched_barrier(0); } while (0)

#define LOAD_A(S, abase, mh) do {                                             \
    _Pragma("unroll")                                                         \
    for (int mi = 0; mi < 4; ++mi)                                            \
        af[mi] = *(const bf16x8*)(smem + ABUF(S) + (abase) + (mh) * 4096 + mi * 1024); \
    } while (0)

#define LOAD_B(S, bbase) do {                                                 \
    _Pragma("unroll")                                                         \
    for (int ni = 0; ni < 4; ++ni)                                            \
        bfr[ni] = *(const bf16x8*)(smem + BBUF(S) + (bbase) + ni * 1024);     \
    } while (0)

#define MFMA16(mh) do {                                                       \
    __builtin_amdgcn_s_setprio(1);                                            \
    _Pragma("unroll")                                                         \
    for (int mi = 0; mi < 4; ++mi)                                            \
        _Pragma("unroll")                                                     \
        for (int ni = 0; ni < 4; ++ni)                                        \
            acc[(mh) * 4 + mi][ni] = __builtin_amdgcn_mfma_f32_16x16x32_bf16( \
                af[mi], bfr[ni], acc[(mh) * 4 + mi][ni], 0, 0, 0);            \
    __builtin_amdgcn_s_setprio(0); } while (0)

    // one K-tile = 4 pinned phases; stages tile t+1 into slot nxtS (phases 0,1)
#define TILE(t, curS, nxtS, DO_STAGE) do {                                    \
    /* phase 0: kk0,mh0 + stage A(t+1) */                                     \
    LOAD_A(curS, a_b0, 0); LOAD_B(curS, b_b0);                                \
    if (DO_STAGE) STAGE_A(nxtS, kb0 + (t) + 1);                               \
    BARRIER_PIN();                                                            \
    MFMA16(0);                                                                \
    BARRIER_PIN();                                                            \
    /* phase 1: kk0,mh1 + stage B(t+1) */                                     \
    LOAD_A(curS, a_b0, 1);                                                    \
    if (DO_STAGE) STAGE_B(nxtS, (t) + 1);                                     \
    BARRIER_PIN();                                                            \
    MFMA16(1);                                                                \
    BARRIER_PIN();                                                            \
    /* phase 2: kk1,mh0 */                                                    \
    LOAD_A(curS, a_b1, 0); LOAD_B(curS, b_b1);                                \
    BARRIER_PIN();                                                            \
    MFMA16(0);                                                                \
    BARRIER_PIN();                                                            \
    /* phase 3: kk1,mh1; drain stages before boundary barrier */              \
    LOAD_A(curS, a_b1, 1);                                                    \
    BARRIER_PIN();                                                            \
    MFMA16(1);                                                                \
    __builtin_amdgcn_sched_barrier(0);                                        \
    __builtin_amdgcn_s_waitcnt(WAITCNT_VM(0));                                \
    __builtin_amdgcn_s_barrier();                                             \
    __builtin_amdgcn_sched_barrier(0);                                        \
    } while (0)

    // prologue: stage tile 0, drain, barrier
    STAGE_A(0, kb0);
    STAGE_B(0, 0);
    __builtin_amdgcn_sched_barrier(0);
    __builtin_amdgcn_s_waitcnt(WAITCNT_VM(0));
    __builtin_amdgcn_s_barrier();
    __builtin_amdgcn_sched_barrier(0);

    // tiles 0..13 (paired for literal buffer slots), then 14 (stages 15), 15 (no stage)
    #pragma unroll 1
    for (int t2 = 0; t2 < 14; t2 += 2) {
        TILE(t2,     0, 1, 1);
        TILE(t2 + 1, 1, 0, 1);
    }
    TILE(14, 0, 1, 1);
    TILE(15, 1, 0, 0);

    // epilogue: C/D layout col = lane&15, row = quad*4 + r
    float* out = partial + (size_t)ks * ((size_t)BATCH * ODIM);
    #pragma unroll
    for (int mi8 = 0; mi8 < 8; ++mi8)
        #pragma unroll
        for (int ni = 0; ni < 4; ++ni)
            #pragma unroll
            for (int r = 0; r < 4; ++r) {
                int rowg = wrow * 128 + mi8 * 16 + quad * 4 + r;
                int colg = nt * BN + wcol * 64 + ni * 16 + row;
                out[(size_t)rowg * ODIM + colg] = acc[mi8][ni][r];
            }
}

// ---- kernel 3: sum KSPLIT partials + bias ----
__global__ void k_reduce_bias(const float* __restrict__ partial,
                              const float* __restrict__ bias,
                              float* __restrict__ out) {
    int t = blockIdx.x * 256 + threadIdx.x;
    const float4* b4 = (const float4*)bias;
    float4 c = b4[t & (ODIM / 4 - 1)];
    float4 r = {c.x, c.y, c.z, c.w};
    #pragma unroll
    for (int k = 0; k < KSPLIT; ++k) {
        const float4* p = (const float4*)(partial + (size_t)k * BATCH * ODIM);
        float4 a = p[t];
        r.x += a.x; r.y += a.y; r.z += a.z; r.w += a.w;
    }
    ((float4*)out)[t] = r;
}

extern "C" void kernel_launch(void* const* d_in, const int* in_sizes, int n_in,
                              void* d_out, int out_size, void* d_ws, size_t ws_size,
                              hipStream_t stream) {
    const float* x      = (const float*)d_in[0];
    const float* blocks = (const float*)d_in[1];
    const float* bias   = (const float*)d_in[2];
    const int*   parts  = (const int*)d_in[3];
    float* out = (float*)d_out;

    char* ws = (char*)d_ws;
    unsigned short* xb      = (unsigned short*)ws;                      // 4 MB
    unsigned short* btb     = (unsigned short*)(ws + (4u << 20));       // 8 MB
    int*            pTr     = (int*)(ws + (12u << 20));                 // 64 KB
    float*          partial = (float*)(ws + (13u << 20));               // 64 MB (ks=8)

    // allow 128 KB dynamic LDS (idempotent; host-side, graph-capture safe)
    static bool attr_set = false;
    if (!attr_set) {
        hipFuncSetAttribute((const void*)k_mosaic_gemm,
                            hipFuncAttributeMaxDynamicSharedMemorySize, 128 * 1024);
        attr_set = true;
    }

    k_convert<<<NB + XCONV_BLKS + PT_BLKS, 256, 0, stream>>>(x, blocks, parts, xb, btb, pTr);
    k_mosaic_gemm<<<dim3(KSPLIT, ODIM / BN), 512, 128 * 1024, stream>>>(xb, btb, pTr, partial);
    k_reduce_bias<<<(BATCH * ODIM) / (256 * 4), 256, 0, stream>>>(partial, bias, out);
}